// Round 2
// baseline (5317.262 us; speedup 1.0000x reference)
//
#include <hip/hip_runtime.h>

#define FHH 38
#define FWW 63
#define NPIX 2394        // 38*63
#define BATCH 8
#define CIN 1024
#define CMID 512
#define NSC 21546        // NPIX*9
#define M_TOT 19152      // BATCH*NPIX
#define K_TOT 9216       // CIN*9
#define PRE_N 2000
#define POST_N 300

// exact anchors (generate_anchors(16,(0.5,1,2),(8,16,32))) — integer-valued, exact in any fp
__device__ const double ANCX1[9] = {-84.,-176.,-360.,-56.,-120.,-248.,-36.,-80.,-168.};
__device__ const double ANCY1[9] = {-40.,-88.,-184.,-56.,-120.,-248.,-80.,-168.,-344.};
__device__ const double ANCX2[9] = {99.,191.,375.,71.,135.,263.,51.,95.,183.};
__device__ const double ANCY2[9] = {55.,103.,199.,71.,135.,263.,95.,183.,359.};

// K0: W_conv [512][1024][3][3] -> Wt[k][co], k=(kh*3+kw)*1024+ci   (fp32, exact copy)
__global__ void wt3x3_kernel(const float* __restrict__ W, float* __restrict__ Wt) {
    int gid = blockIdx.x * 256 + threadIdx.x;
    if (gid >= K_TOT * CMID) return;
    int co = gid & 511;
    int k  = gid >> 9;
    int pl = k >> 10;        // kh*3+kw
    int ci = k & 1023;
    Wt[gid] = W[((size_t)co * CIN + ci) * 9 + pl];
}

// K0b: W_cls[18][512], W_bbox[36][512] -> Wt2pD[k][64] double (n<18 cls, 18..53 bbox, pad 0)
__global__ void wt1x1_kernel(const float* __restrict__ Wc, const float* __restrict__ Wb,
                             double* __restrict__ Wt2pD) {
    int gid = blockIdx.x * 256 + threadIdx.x;
    if (gid >= CMID * 64) return;
    int n = gid & 63, k = gid >> 6;
    double v = 0.0;
    if (n < 18)      v = (double)Wc[(size_t)n * CMID + k];
    else if (n < 54) v = (double)Wb[(size_t)(n - 18) * CMID + k];
    Wt2pD[gid] = v;
}

// K1: implicit-GEMM FP64-accumulate 3x3 conv + bias + relu. M=19152, N=512, K=9216.
// Tile 64x128, BK=32, 256 threads, 4x8 double acc/thread. Output NHWC double [m][512].
__global__ __launch_bounds__(256) void conv3x3_kernel(
    const float* __restrict__ x, const float* __restrict__ Wt,
    const float* __restrict__ bconv, double* __restrict__ feat) {
    __shared__ double As[32 * 64];   // 16 KB
    __shared__ double Bs[32 * 128];  // 32 KB
    const int tid = threadIdx.x;
    const int n0 = blockIdx.x * 128;
    const int m0 = blockIdx.y * 64;
    const int mm = tid & 63;
    const int t6 = tid >> 6;          // 0..3
    const int m = m0 + mm;
    const bool vm = (m < M_TOT);
    int b = 0, yy = 0, xx = 0;
    if (vm) { b = m / NPIX; int r = m - b * NPIX; yy = r / FWW; xx = r - yy * FWW; }
    const int tm = tid & 15;
    const int tn = tid >> 4;
    const int bn_k = tid >> 5;        // 0..7
    const int bn_n = (tid & 31) << 2; // 0..124

    double acc[4][8];
#pragma unroll
    for (int i = 0; i < 4; ++i)
#pragma unroll
        for (int j = 0; j < 8; ++j) acc[i][j] = 0.0;

    for (int kc = 0; kc < 288; ++kc) {
        const int pl = kc >> 5;
        const int kh = pl / 3, kw = pl - kh * 3;
        const int ci0 = (kc & 31) << 5;
        const int iy = yy + kh - 1, ix = xx + kw - 1;
        const bool ok = vm && (iy >= 0) && (iy < FHH) && (ix >= 0) && (ix < FWW);
        const float* ap = x + ((size_t)(b * CIN + ci0 + t6)) * NPIX + iy * FWW + ix;
#pragma unroll
        for (int r = 0; r < 8; ++r) {
            float v = ok ? ap[(size_t)r * 4 * NPIX] : 0.f;
            As[(t6 + r * 4) * 64 + mm] = (double)v;
        }
        const int k0 = kc << 5;
        const float4* wp = (const float4*)(Wt + (size_t)(k0 + bn_k) * CMID + n0 + bn_n);
#pragma unroll
        for (int r = 0; r < 4; ++r) {
            float4 v = wp[(size_t)r * 1024];  // r*8 rows * 128 float4/row
            double* bd = &Bs[(bn_k + r * 8) * 128 + bn_n];
            bd[0] = (double)v.x; bd[1] = (double)v.y; bd[2] = (double)v.z; bd[3] = (double)v.w;
        }
        __syncthreads();
#pragma unroll
        for (int kk = 0; kk < 32; ++kk) {
            const double* ar = &As[kk * 64 + (tm << 2)];
            const double* br = &Bs[kk * 128 + (tn << 2)];
            double a4[4] = {ar[0], ar[1], ar[2], ar[3]};
            double b8[8] = {br[0], br[1], br[2], br[3], br[64], br[65], br[66], br[67]};
#pragma unroll
            for (int mi = 0; mi < 4; ++mi)
#pragma unroll
                for (int nj = 0; nj < 8; ++nj)
                    acc[mi][nj] = fma(a4[mi], b8[nj], acc[mi][nj]);
        }
        __syncthreads();
    }
#pragma unroll
    for (int mi = 0; mi < 4; ++mi) {
        int mg = m0 + (tm << 2) + mi;
        if (mg < M_TOT) {
            double* dst = feat + (size_t)mg * CMID + n0;
#pragma unroll
            for (int nj = 0; nj < 8; ++nj) {
                int col = (nj < 4) ? ((tn << 2) + nj) : (64 + (tn << 2) + nj - 4);
                double s = acc[mi][nj] + (double)bconv[n0 + col];
                dst[col] = fmax(s, 0.0);
            }
        }
    }
}

// K2: 1x1 convs (cls 18 + bbox 36 as 54 outputs), fp64. featD NHWC -> out54D[m][64]
__global__ __launch_bounds__(256) void conv1x1_kernel(
    const double* __restrict__ feat, const double* __restrict__ Wt2pD,
    const float* __restrict__ bcls, const float* __restrict__ bbx,
    double* __restrict__ out54) {
    __shared__ double As[4 * 512];   // 16 KB
    __shared__ double Bsh[64 * 64];  // 32 KB
    int tid = threadIdx.x;
    int m0 = blockIdx.x * 4;
    for (int off = tid; off < 2048; off += 256) As[off] = feat[(size_t)m0 * CMID + off];
    int p = tid >> 6, n = tid & 63;
    double acc = 0.0;
    for (int c = 0; c < 8; ++c) {
        __syncthreads();
        for (int off = tid; off < 4096; off += 256) Bsh[off] = Wt2pD[c * 4096 + off];
        __syncthreads();
        const double* ap = &As[p * 512 + c * 64];
#pragma unroll 8
        for (int k2 = 0; k2 < 64; ++k2) acc = fma(ap[k2], Bsh[k2 * 64 + n], acc);
    }
    if (n < 54) {
        double bias = (double)((n < 18) ? bcls[n] : bbx[n - 18]);
        out54[(size_t)(m0 + p) * 64 + n] = acc + bias;
    }
}

// K2b: softmax-pair score + bbox_transform_inv + clip, all fp64
__global__ void proposals_kernel(const double* __restrict__ out54, const float* __restrict__ iminfo,
                                 double* __restrict__ scoresD, double* __restrict__ propsD) {
    int gid = blockIdx.x * 256 + threadIdx.x;
    if (gid >= BATCH * NSC) return;
    int b = gid / NSC;
    int rem = gid - b * NSC;
    int p = rem / 9;
    int a = rem - p * 9;
    int y = p / FWW, x = p - y * FWW;
    int m = b * NPIX + p;
    const double* row = out54 + (size_t)m * 64;
    double s0 = row[a], s1 = row[9 + a];
    double mx = fmax(s0, s1);
    double e0 = exp(s0 - mx), e1 = exp(s1 - mx);
    scoresD[gid] = e1 / (e0 + e1);
    double dx = row[18 + 4 * a], dy = row[19 + 4 * a], dw = row[20 + 4 * a], dh = row[21 + 4 * a];
    double ax1 = x * 16.0 + ANCX1[a], ay1 = y * 16.0 + ANCY1[a];
    double ax2 = x * 16.0 + ANCX2[a], ay2 = y * 16.0 + ANCY2[a];
    double w = ax2 - ax1 + 1.0, h = ay2 - ay1 + 1.0;
    double cx = ax1 + 0.5 * w, cy = ay1 + 0.5 * h;
    double px = dx * w + cx, py = dy * h + cy;
    double pw = exp(dw) * w, ph = exp(dh) * h;
    double imh = (double)iminfo[b * 3 + 0], imw = (double)iminfo[b * 3 + 1];
    double x1 = fmin(fmax(px - 0.5 * pw, 0.0), imw - 1.0);
    double y1 = fmin(fmax(py - 0.5 * ph, 0.0), imh - 1.0);
    double x2 = fmin(fmax(px + 0.5 * pw, 0.0), imw - 1.0);
    double y2 = fmin(fmax(py + 0.5 * ph, 0.0), imh - 1.0);
    double* o = propsD + (size_t)gid * 4;
    o[0] = x1; o[1] = y1; o[2] = x2; o[3] = y2;
}

// K3: exact top-2000, stable lower-index ties. key = (double_score_bits & ~0x7FFF) | (~i & 0x7FFF)
// (scores positive doubles -> bit pattern is order-monotone; low 15 mantissa bits sacrificed for
//  the index tie-break: collisions need relative score gaps < 2^-37 — negligible).
__global__ __launch_bounds__(256) void select_kernel(const double* __restrict__ scoresD,
                                                     const double* __restrict__ propsD,
                                                     double* __restrict__ boxesD) {
    __shared__ unsigned int hist4[4][256];
    __shared__ unsigned int histf[256];
    __shared__ unsigned long long keys[2048];
    __shared__ unsigned long long sh_thr;
    __shared__ int sh_need;
    __shared__ int cnt;
    const int b = blockIdx.x, tid = threadIdx.x;
    const int w4 = tid >> 6;
    const double* sc = scoresD + (size_t)b * NSC;

    unsigned long long prefix = 0ull;
    int need = PRE_N;
    for (int d = 7; d >= 0; --d) {
        for (int z = tid; z < 1024; z += 256) ((unsigned int*)hist4)[z] = 0u;
        __syncthreads();
        const int shift = d * 8;
        const unsigned long long maskAbove = (d == 7) ? 0ull : (~0ull << (shift + 8));
        for (int i = tid; i < NSC; i += 256) {
            unsigned long long sb = (unsigned long long)__double_as_longlong(sc[i]);
            unsigned long long key = (sb & ~0x7FFFull) | (unsigned long long)((~i) & 0x7FFF);
            if (((key ^ prefix) & maskAbove) == 0ull)
                atomicAdd(&hist4[w4][(unsigned int)(key >> shift) & 255u], 1u);
        }
        __syncthreads();
        histf[tid] = hist4[0][tid] + hist4[1][tid] + hist4[2][tid] + hist4[3][tid];
        __syncthreads();
        if (tid == 0) {
            int acc = 0, v = 255;
            for (; v > 0; --v) {
                int c = (int)histf[v];
                if (acc + c >= need) break;
                acc += c;
            }
            sh_thr = prefix | ((unsigned long long)(unsigned int)v << shift);
            sh_need = need - acc;
        }
        __syncthreads();
        prefix = sh_thr;
        need = sh_need;
        __syncthreads();
    }
    if (tid == 0) cnt = 0;
    __syncthreads();
    for (int i = tid; i < NSC; i += 256) {
        unsigned long long sb = (unsigned long long)__double_as_longlong(sc[i]);
        unsigned long long key = (sb & ~0x7FFFull) | (unsigned long long)((~i) & 0x7FFF);
        if (key >= prefix) {
            int slot = atomicAdd(&cnt, 1);
            if (slot < 2048) keys[slot] = key;
        }
    }
    __syncthreads();
    int c0 = cnt;
    for (int i = tid; i < 2048; i += 256)
        if (i >= c0) keys[i] = 0ull;
    // bitonic sort, descending
    for (int k2 = 2; k2 <= 2048; k2 <<= 1)
        for (int j = k2 >> 1; j > 0; j >>= 1) {
            __syncthreads();
            for (int i = tid; i < 2048; i += 256) {
                int l = i ^ j;
                if (l > i) {
                    unsigned long long a = keys[i], c = keys[l];
                    bool up = (i & k2) == 0;
                    if (up ? (a < c) : (a > c)) { keys[i] = c; keys[l] = a; }
                }
            }
        }
    __syncthreads();
    const double* pr = propsD + (size_t)b * NSC * 4;
    double* bs = boxesD + (size_t)b * PRE_N * 4;
    for (int r = tid; r < PRE_N; r += 256) {
        int idx = (int)((~keys[r]) & 0x7FFF);
        if (idx >= NSC) idx = 0;
        bs[r * 4 + 0] = pr[(size_t)idx * 4 + 0];
        bs[r * 4 + 1] = pr[(size_t)idx * 4 + 1];
        bs[r * 4 + 2] = pr[(size_t)idx * 4 + 2];
        bs[r * 4 + 3] = pr[(size_t)idx * 4 + 3];
    }
}

// K4a: fp64 suppression bitmask. Interleaved: word w (0..31), bit t -> j = t*32 + w.
__global__ __launch_bounds__(256) void iou_mask_kernel(const double* __restrict__ boxesD,
                                                       unsigned long long* __restrict__ supmask) {
    __shared__ double bx[PRE_N * 4];   // 64000 B
    int b = blockIdx.x;
    int i0 = blockIdx.y * 80;
    const double* src = boxesD + (size_t)b * PRE_N * 4;
    for (int o = threadIdx.x; o < PRE_N * 4; o += 256) bx[o] = src[o];
    __syncthreads();
    int ty = threadIdx.x >> 5, jw = threadIdx.x & 31;
    for (int ii = ty; ii < 80; ii += 8) {
        int i = i0 + ii;
        double bix1 = bx[i * 4 + 0], biy1 = bx[i * 4 + 1], bix2 = bx[i * 4 + 2], biy2 = bx[i * 4 + 3];
        double areai = (bix2 - bix1 + 1.0) * (biy2 - biy1 + 1.0);
        unsigned long long bits = 0ull;
        for (int t = 0; t < 64; ++t) {
            int j = t * 32 + jw;
            if (j > i && j < PRE_N) {
                double bjx1 = bx[j * 4 + 0], bjy1 = bx[j * 4 + 1], bjx2 = bx[j * 4 + 2], bjy2 = bx[j * 4 + 3];
                double iw = fmin(bix2, bjx2) - fmax(bix1, bjx1) + 1.0; iw = fmax(iw, 0.0);
                double ih = fmin(biy2, bjy2) - fmax(biy1, bjy1) + 1.0; ih = fmax(ih, 0.0);
                double inter = iw * ih;
                double areaj = (bjx2 - bjx1 + 1.0) * (bjy2 - bjy1 + 1.0);
                double iou = inter / (areai + areaj - inter);
                if (iou > 0.7) bits |= (1ull << t);
            }
        }
        supmask[((size_t)b * PRE_N + i) * 32 + jw] = bits;
    }
}

// K4b: sequential greedy suppression + first-300-kept (stable -inf fill) + fp32 output
__global__ void nms_final_kernel(const unsigned long long* __restrict__ supmask,
                                 const double* __restrict__ boxesD,
                                 float* __restrict__ out) {
    int b = blockIdx.x;
    int lane = threadIdx.x;     // 64 threads
    int w = lane & 31;
    const unsigned long long* mask = supmask + (size_t)b * PRE_N * 32;
    int nbits = (w < 16) ? 63 : 62;                // j = t*32+w < 2000
    unsigned long long kw = (1ull << nbits) - 1ull;
    unsigned long long rr[16];
#pragma unroll
    for (int d2 = 0; d2 < 16; ++d2) rr[d2] = mask[d2 * 32 + w];
    for (int i = 0; i < PRE_N; i += 16) {
#pragma unroll
        for (int u = 0; u < 16; ++u) {
            int ii = i + u;
            unsigned long long rcur = rr[u];
            int ip = ii + 16;
            rr[u] = (ip < PRE_N) ? mask[ip * 32 + w] : 0ull;
            unsigned long long kword = __shfl(kw, ii & 31);
            if ((kword >> (ii >> 5)) & 1ull) kw &= ~rcur;
        }
    }
    __shared__ unsigned long long keepw[32];
    __shared__ int pos[POST_N];
    if (lane < 32) keepw[lane] = kw;
    __syncthreads();
    if (lane == 0) {
        int c2 = 0;
        for (int j = 0; j < PRE_N && c2 < POST_N; ++j)
            if ((keepw[j & 31] >> (j >> 5)) & 1ull) pos[c2++] = j;
        for (int j = 0; j < PRE_N && c2 < POST_N; ++j)
            if (!((keepw[j & 31] >> (j >> 5)) & 1ull)) pos[c2++] = j;
    }
    __syncthreads();
    for (int r = lane; r < POST_N; r += 64) {
        int p = pos[r];
        const double* bxp = boxesD + ((size_t)b * PRE_N + p) * 4;
        float* o = out + ((size_t)b * POST_N + r) * 5;
        o[0] = (float)b; o[1] = (float)bxp[0]; o[2] = (float)bxp[1];
        o[3] = (float)bxp[2]; o[4] = (float)bxp[3];
    }
    if (b == 0 && lane == 0) { out[BATCH * POST_N * 5] = 0.f; out[BATCH * POST_N * 5 + 1] = 0.f; }
}

extern "C" void kernel_launch(void* const* d_in, const int* in_sizes, int n_in,
                              void* d_out, int out_size, void* d_ws, size_t ws_size,
                              hipStream_t stream) {
    (void)in_sizes; (void)n_in; (void)out_size; (void)ws_size;
    const float* base_feat = (const float*)d_in[0];
    const float* im_info   = (const float*)d_in[1];
    const float* W_conv    = (const float*)d_in[4];
    const float* b_conv    = (const float*)d_in[5];
    const float* W_cls     = (const float*)d_in[6];
    const float* b_cls     = (const float*)d_in[7];
    const float* W_bbox    = (const float*)d_in[8];
    const float* b_bbox    = (const float*)d_in[9];
    float* out = (float*)d_out;

    // workspace layout (doubles first; ~113.4 MiB total)
    double* featD   = (double*)d_ws;            // 9,805,824 d
    double* out54D  = featD + 9805824;          // 1,225,728 d
    double* scoresD = out54D + 1225728;         //   172,368 d
    double* propsD  = scoresD + 172368;         //   689,472 d
    double* boxesD  = propsD + 689472;          //    64,000 d
    double* Wt2pD   = boxesD + 64000;           //    32,768 d
    unsigned long long* supmask = (unsigned long long*)(Wt2pD + 32768); // 512,000 u64
    float* Wt       = (float*)(supmask + 512000);                       // 4,718,592 f32

    wt3x3_kernel<<<(K_TOT * CMID + 255) / 256, 256, 0, stream>>>(W_conv, Wt);
    wt1x1_kernel<<<(CMID * 64 + 255) / 256, 256, 0, stream>>>(W_cls, W_bbox, Wt2pD);
    conv3x3_kernel<<<dim3(4, 300), 256, 0, stream>>>(base_feat, Wt, b_conv, featD);
    conv1x1_kernel<<<M_TOT / 4, 256, 0, stream>>>(featD, Wt2pD, b_cls, b_bbox, out54D);
    proposals_kernel<<<(BATCH * NSC + 255) / 256, 256, 0, stream>>>(out54D, im_info, scoresD, propsD);
    select_kernel<<<BATCH, 256, 0, stream>>>(scoresD, propsD, boxesD);
    iou_mask_kernel<<<dim3(BATCH, 25), 256, 0, stream>>>(boxesD, supmask);
    nms_final_kernel<<<BATCH, 64, 0, stream>>>(supmask, boxesD, out);
}